// Round 1
// baseline (172.957 us; speedup 1.0000x reference)
//
#include <hip/hip_runtime.h>
#include <math.h>

// Problem constants (static per reference)
#define BB 8
#define NN 384
#define FF 64
#define TT 192
#define TAU 192
#define NSRC 383          // T + TAU - 1
#define NSINK 192
#define SS 5
#define NEDGE 441600      // B * 55200

// ---------------- prep: per-node projections (fold b1 into A) ----------------
__global__ __launch_bounds__(64) void prep_nodes(
    const float* __restrict__ nodes, const float* __restrict__ w1,
    const float* __restrict__ b1, float* __restrict__ A, float* __restrict__ Bv) {
  const int bn = blockIdx.x;      // 0 .. B*N-1
  const int k = threadIdx.x;      // 0 .. 63
  __shared__ float nd[FF];
  nd[k] = nodes[bn * FF + k];
  __syncthreads();
  float a = b1[k];
  float bb = 0.f;
#pragma unroll
  for (int f = 0; f < FF; ++f) {
    a  = fmaf(nd[f], w1[f * FF + k], a);
    bb = fmaf(nd[f], w1[(FF + f) * FF + k], bb);
  }
  A[bn * FF + k] = a;
  Bv[bn * FF + k] = bb;
}

// ------------- prep: fold LN scales/biases into weights -------------
// W2gT[j][k] = g1[k] * w2[k][j]
// cb[j]      = b2[j] + sum_k be1[k] * w2[k][j]
// gw[j]      = g2[j] * w3[j]
// cwsgw[0]   = b3 + sum_j be2[j]*w3[j]   (cw)
// cwsgw[1]   = sum_j gw[j]               (sgw)
__global__ __launch_bounds__(64) void prep_weights(
    const float* __restrict__ w2, const float* __restrict__ b2,
    const float* __restrict__ g1, const float* __restrict__ be1,
    const float* __restrict__ g2, const float* __restrict__ be2,
    const float* __restrict__ w3, const float* __restrict__ b3,
    float* __restrict__ W2gT, float* __restrict__ cb,
    float* __restrict__ gw, float* __restrict__ cwsgw) {
  const int j = threadIdx.x;
  float cbj = b2[j];
  for (int k = 0; k < FF; ++k) {
    const float w = w2[k * FF + j];
    W2gT[j * FF + k] = g1[k] * w;
    cbj = fmaf(be1[k], w, cbj);
  }
  cb[j] = cbj;
  const float gwj = g2[j] * w3[j];
  gw[j] = gwj;
  __shared__ float sA[FF], sB[FF];
  sA[j] = gwj;
  sB[j] = be2[j] * w3[j];
  __syncthreads();
  if (j == 0) {
    float a = 0.f, bq = 0.f;
    for (int i = 0; i < FF; ++i) { a += sA[i]; bq += sB[i]; }
    cwsgw[0] = b3[0] + bq;
    cwsgw[1] = a;
  }
}

// ---------------- main: per-edge MLP -> logit grid ----------------
__global__ __launch_bounds__(256) void edge_mlp(
    const float* __restrict__ A, const float* __restrict__ Bv,
    const float* __restrict__ W2gT, const float* __restrict__ cb,
    const float* __restrict__ gw, const float* __restrict__ cwsgw,
    const int* __restrict__ bidx, const int* __restrict__ ridx,
    const int* __restrict__ cidx, float* __restrict__ L) {
  const int e = blockIdx.x * 256 + threadIdx.x;
  if (e >= NEDGE) return;
  const int b = bidx[e];
  const int r = ridx[e];
  const int c = cidx[e];

  const float4* pa = (const float4*)(A + (b * NN + r) * FF);
  const float4* pb = (const float4*)(Bv + (b * NN + c) * FF);

  float u[FF];
  float s = 0.f;
#pragma unroll
  for (int q = 0; q < 16; ++q) {
    const float4 av = pa[q];
    const float4 bv4 = pb[q];
    float x0 = fmaxf(av.x + bv4.x, 0.f);
    float x1 = fmaxf(av.y + bv4.y, 0.f);
    float x2 = fmaxf(av.z + bv4.z, 0.f);
    float x3 = fmaxf(av.w + bv4.w, 0.f);
    u[4 * q + 0] = x0; u[4 * q + 1] = x1; u[4 * q + 2] = x2; u[4 * q + 3] = x3;
    s += x0; s += x1; s += x2; s += x3;
  }
  const float mu1 = s * (1.f / FF);
  float vs = 0.f;
#pragma unroll
  for (int k = 0; k < FF; ++k) {
    const float d = u[k] - mu1;
    vs = fmaf(d, d, vs);
    u[k] = d;
  }
  const float rstd1 = 1.f / sqrtf(vs * (1.f / FF) + 1e-5f);
#pragma unroll
  for (int k = 0; k < FF; ++k) u[k] *= rstd1;   // h' (g1/be1 folded into W2gT/cb)

  float s1 = 0.f, s2 = 0.f, s3 = 0.f;
#pragma unroll 1
  for (int jb = 0; jb < FF; jb += 8) {
    float t[8];
#pragma unroll
    for (int jj = 0; jj < 8; ++jj) t[jj] = cb[jb + jj];
#pragma unroll
    for (int jj = 0; jj < 8; ++jj) {
      const float* __restrict__ wr = W2gT + (jb + jj) * FF;
      float acc = t[jj];
#pragma unroll
      for (int k = 0; k < FF; ++k) acc = fmaf(u[k], wr[k], acc);
      t[jj] = acc;
    }
#pragma unroll
    for (int jj = 0; jj < 8; ++jj) {
      const float tr = fmaxf(t[jj], 0.f);
      s1 += tr;
      s2 = fmaf(tr, tr, s2);
      s3 = fmaf(tr, gw[jb + jj], s3);
    }
  }
  const float mu2 = s1 * (1.f / FF);
  const float var2 = s2 * (1.f / FF) - mu2 * mu2;
  const float rstd2 = 1.f / sqrtf(var2 + 1e-5f);
  const float logit = fmaf(rstd2, s3 - mu2 * cwsgw[1], cwsgw[0]);

  L[(b * NSINK + (r - TT)) * NSRC + c] = logit;
}

// ---------------- zero the output ----------------
__global__ __launch_bounds__(256) void zero_out(float4* __restrict__ out) {
  const int i = blockIdx.x * 256 + threadIdx.x;
  out[i] = make_float4(0.f, 0.f, 0.f, 0.f);
}

// ---------------- argmax over sources + scatter ones ----------------
__global__ __launch_bounds__(256) void argmax_scatter(
    const float* __restrict__ L, const float* __restrict__ gum,
    float* __restrict__ out) {
  const int task = blockIdx.x * 4 + (threadIdx.x >> 6);  // ((s*B+b)*192+row)
  const int lane = threadIdx.x & 63;
  const int row = task % NSINK;
  const int sb = task / NSINK;   // s*B + b
  const int b = sb & 7;
  const int r = row + TT;

  const float* __restrict__ lrow = L + (b * NSINK + row) * NSRC;
  const float* __restrict__ grow = gum + task * NSRC;

  float bv = -INFINITY;
  int bi = 0;
  for (int c = lane; c < r; c += 64) {
    const float v = lrow[c] + grow[c];
    if (v > bv) { bv = v; bi = c; }   // strict > keeps smallest index per lane
  }
#pragma unroll
  for (int off = 32; off > 0; off >>= 1) {
    const float ov = __shfl_xor(bv, off, 64);
    const int oi = __shfl_xor(bi, off, 64);
    if (ov > bv || (ov == bv && oi < bi)) { bv = ov; bi = oi; }
  }
  if (lane == 0) out[(b * NN + r) * NN + bi] = 1.0f;
}

extern "C" void kernel_launch(void* const* d_in, const int* in_sizes, int n_in,
                              void* d_out, int out_size, void* d_ws, size_t ws_size,
                              hipStream_t stream) {
  const float* nodes = (const float*)d_in[0];
  const float* w1 = (const float*)d_in[1];
  const float* b1 = (const float*)d_in[2];
  const float* g1 = (const float*)d_in[3];
  const float* be1 = (const float*)d_in[4];
  const float* w2 = (const float*)d_in[5];
  const float* b2 = (const float*)d_in[6];
  const float* g2 = (const float*)d_in[7];
  const float* be2 = (const float*)d_in[8];
  const float* w3 = (const float*)d_in[9];
  const float* b3 = (const float*)d_in[10];
  const float* gum = (const float*)d_in[11];
  const int* bidx = (const int*)d_in[12];
  const int* ridx = (const int*)d_in[13];
  const int* cidx = (const int*)d_in[14];
  float* out = (float*)d_out;

  // workspace layout (floats)
  float* ws = (float*)d_ws;
  float* A = ws;                       // 8*384*64 = 196608
  float* Bv = A + BB * NN * FF;        // 196608
  float* W2gT = Bv + BB * NN * FF;     // 4096
  float* cb = W2gT + FF * FF;          // 64
  float* gw = cb + FF;                 // 64
  float* cwsgw = gw + FF;              // 2 (+pad)
  float* L = ws + 397456;              // 8*192*383 = 588288, 16-float aligned
  (void)ws_size; (void)n_in; (void)in_sizes; (void)out_size;

  hipLaunchKernelGGL(prep_nodes, dim3(BB * NN), dim3(64), 0, stream,
                     nodes, w1, b1, A, Bv);
  hipLaunchKernelGGL(prep_weights, dim3(1), dim3(64), 0, stream,
                     w2, b2, g1, be1, g2, be2, w3, b3, W2gT, cb, gw, cwsgw);
  hipLaunchKernelGGL(zero_out, dim3((BB * NN * NN) / 4 / 256), dim3(256), 0, stream,
                     (float4*)out);
  hipLaunchKernelGGL(edge_mlp, dim3(NEDGE / 256), dim3(256), 0, stream,
                     A, Bv, W2gT, cb, gw, cwsgw, bidx, ridx, cidx, L);
  hipLaunchKernelGGL(argmax_scatter, dim3((SS * BB * NSINK) / 4), dim3(256), 0, stream,
                     L, gum, out);
}

// Round 2
// 171.604 us; speedup vs baseline: 1.0079x; 1.0079x over previous
//
#include <hip/hip_runtime.h>
#include <math.h>
#include <stdint.h>

// Problem constants (static per reference)
#define BB 8
#define NN 384
#define FF 64
#define TT 192
#define TAU 192
#define NSRC 383          // T + TAU - 1
#define NSINK 192
#define SS 5
#define NEDGE 441600      // B * 55200

#define CONST_AS __attribute__((address_space(4)))
typedef const CONST_AS float cfloat;

// ---------------- prep: per-node projections + weight folding ----------------
// blocks 0..B*N-1: A/B projections (b1 folded into A)
// block B*N: fold LN scales/biases into weights:
//   W2gT[j][k] = g1[k]*w2[k][j];  cb[j] = b2[j] + sum_k be1[k]*w2[k][j]
//   gw[j] = g2[j]*w3[j];  cwsgw = {b3 + sum_j be2[j]*w3[j], sum_j gw[j]}
__global__ __launch_bounds__(64) void prep_all(
    const float* __restrict__ nodes, const float* __restrict__ w1,
    const float* __restrict__ b1,
    const float* __restrict__ w2, const float* __restrict__ b2,
    const float* __restrict__ g1, const float* __restrict__ be1,
    const float* __restrict__ g2, const float* __restrict__ be2,
    const float* __restrict__ w3, const float* __restrict__ b3,
    float* __restrict__ A, float* __restrict__ Bv,
    float* __restrict__ W2gT, float* __restrict__ cb,
    float* __restrict__ gw, float* __restrict__ cwsgw) {
  const int bn = blockIdx.x;
  if (bn < BB * NN) {
    const int k = threadIdx.x;
    __shared__ float nd[FF];
    nd[k] = nodes[bn * FF + k];
    __syncthreads();
    float a = b1[k];
    float bb = 0.f;
#pragma unroll
    for (int f = 0; f < FF; ++f) {
      a  = fmaf(nd[f], w1[f * FF + k], a);
      bb = fmaf(nd[f], w1[(FF + f) * FF + k], bb);
    }
    A[bn * FF + k] = a;
    Bv[bn * FF + k] = bb;
  } else {
    const int j = threadIdx.x;
    float cbj = b2[j];
    for (int k = 0; k < FF; ++k) {
      const float w = w2[k * FF + j];
      W2gT[j * FF + k] = g1[k] * w;
      cbj = fmaf(be1[k], w, cbj);
    }
    cb[j] = cbj;
    const float gwj = g2[j] * w3[j];
    gw[j] = gwj;
    __shared__ float sA[FF], sB[FF];
    sA[j] = gwj;
    sB[j] = be2[j] * w3[j];
    __syncthreads();
    if (j == 0) {
      float a = 0.f, bq = 0.f;
      for (int i = 0; i < FF; ++i) { a += sA[i]; bq += sB[i]; }
      cwsgw[0] = b3[0] + bq;
      cwsgw[1] = a;
    }
  }
}

// ---------------- main: zero out + per-edge MLP -> logit grid ----------------
__global__ __launch_bounds__(256, 4) void edge_mlp(
    const float* __restrict__ A, const float* __restrict__ Bv,
    const float* __restrict__ W2gTg, const float* __restrict__ cbg,
    const float* __restrict__ gwg, const float* __restrict__ cwsgwg,
    const int* __restrict__ bidx, const int* __restrict__ ridx,
    const int* __restrict__ cidx, float* __restrict__ L,
    float4* __restrict__ outv) {
  const int e = blockIdx.x * 256 + threadIdx.x;

  // fused zeroing of the output grid (B*N*N floats = 294912 float4)
  if (e < (BB * NN * NN) / 4) outv[e] = make_float4(0.f, 0.f, 0.f, 0.f);
  if (e >= NEDGE) return;

  // constant-AS views -> uniform-address reads become s_load (SMEM pipe)
  cfloat* W2gT = (cfloat*)(uintptr_t)W2gTg;
  cfloat* cb = (cfloat*)(uintptr_t)cbg;
  cfloat* gw = (cfloat*)(uintptr_t)gwg;
  cfloat* cwsgw = (cfloat*)(uintptr_t)cwsgwg;

  const int b = bidx[e];
  const int r = ridx[e];
  const int c = cidx[e];

  const float4* pa = (const float4*)(A + (b * NN + r) * FF);
  const float4* pb = (const float4*)(Bv + (b * NN + c) * FF);

  float u[FF];
  float s = 0.f;
#pragma unroll
  for (int q = 0; q < 16; ++q) {
    const float4 av = pa[q];
    const float4 bv4 = pb[q];
    float x0 = fmaxf(av.x + bv4.x, 0.f);
    float x1 = fmaxf(av.y + bv4.y, 0.f);
    float x2 = fmaxf(av.z + bv4.z, 0.f);
    float x3 = fmaxf(av.w + bv4.w, 0.f);
    u[4 * q + 0] = x0; u[4 * q + 1] = x1; u[4 * q + 2] = x2; u[4 * q + 3] = x3;
    s += x0; s += x1; s += x2; s += x3;
  }
  const float mu1 = s * (1.f / FF);
  float vs = 0.f;
#pragma unroll
  for (int k = 0; k < FF; ++k) {
    const float d = u[k] - mu1;
    vs = fmaf(d, d, vs);
    u[k] = d;            // keep UN-normalized; rstd1 folded into row epilogue
  }
  const float rstd1 = 1.f / sqrtf(vs * (1.f / FF) + 1e-5f);

  float s1 = 0.f, s2 = 0.f, s3 = 0.f;
#pragma unroll 1
  for (int jb = 0; jb < FF; jb += 4) {
#pragma unroll
    for (int jj = 0; jj < 4; ++jj) {
      cfloat* wr = W2gT + (jb + jj) * FF;
      // 4 partial accumulators for ILP within the row
      float a0 = 0.f, a1 = 0.f, a2 = 0.f, a3 = 0.f;
#pragma unroll
      for (int k = 0; k < FF; k += 4) {
        a0 = fmaf(u[k + 0], wr[k + 0], a0);
        a1 = fmaf(u[k + 1], wr[k + 1], a1);
        a2 = fmaf(u[k + 2], wr[k + 2], a2);
        a3 = fmaf(u[k + 3], wr[k + 3], a3);
      }
      const float dot = (a0 + a1) + (a2 + a3);
      const float pre = fmaf(dot, rstd1, cb[jb + jj]);
      const float tr = fmaxf(pre, 0.f);
      s1 += tr;
      s2 = fmaf(tr, tr, s2);
      s3 = fmaf(tr, gw[jb + jj], s3);
    }
  }
  const float mu2 = s1 * (1.f / FF);
  const float var2 = s2 * (1.f / FF) - mu2 * mu2;
  const float rstd2 = 1.f / sqrtf(var2 + 1e-5f);
  const float logit = fmaf(rstd2, s3 - mu2 * cwsgw[1], cwsgw[0]);

  L[(b * NSINK + (r - TT)) * NSRC + c] = logit;
}

// ---------------- argmax over sources + scatter ones ----------------
__global__ __launch_bounds__(256) void argmax_scatter(
    const float* __restrict__ L, const float* __restrict__ gum,
    float* __restrict__ out) {
  const int task = blockIdx.x * 4 + (threadIdx.x >> 6);  // ((s*B+b)*192+row)
  const int lane = threadIdx.x & 63;
  const int row = task % NSINK;
  const int sb = task / NSINK;   // s*B + b
  const int b = sb & 7;
  const int r = row + TT;

  const float* __restrict__ lrow = L + (b * NSINK + row) * NSRC;
  const float* __restrict__ grow = gum + task * NSRC;

  float bv = -INFINITY;
  int bi = 0;
  for (int c = lane; c < r; c += 64) {
    const float v = lrow[c] + grow[c];
    if (v > bv) { bv = v; bi = c; }   // strict > keeps smallest index per lane
  }
#pragma unroll
  for (int off = 32; off > 0; off >>= 1) {
    const float ov = __shfl_xor(bv, off, 64);
    const int oi = __shfl_xor(bi, off, 64);
    if (ov > bv || (ov == bv && oi < bi)) { bv = ov; bi = oi; }
  }
  if (lane == 0) out[(b * NN + r) * NN + bi] = 1.0f;
}

extern "C" void kernel_launch(void* const* d_in, const int* in_sizes, int n_in,
                              void* d_out, int out_size, void* d_ws, size_t ws_size,
                              hipStream_t stream) {
  const float* nodes = (const float*)d_in[0];
  const float* w1 = (const float*)d_in[1];
  const float* b1 = (const float*)d_in[2];
  const float* g1 = (const float*)d_in[3];
  const float* be1 = (const float*)d_in[4];
  const float* w2 = (const float*)d_in[5];
  const float* b2 = (const float*)d_in[6];
  const float* g2 = (const float*)d_in[7];
  const float* be2 = (const float*)d_in[8];
  const float* w3 = (const float*)d_in[9];
  const float* b3 = (const float*)d_in[10];
  const float* gum = (const float*)d_in[11];
  const int* bidx = (const int*)d_in[12];
  const int* ridx = (const int*)d_in[13];
  const int* cidx = (const int*)d_in[14];
  float* out = (float*)d_out;

  // workspace layout (floats)
  float* ws = (float*)d_ws;
  float* A = ws;                       // 8*384*64 = 196608
  float* Bv = A + BB * NN * FF;        // 196608
  float* W2gT = Bv + BB * NN * FF;     // 4096
  float* cb = W2gT + FF * FF;          // 64
  float* gw = cb + FF;                 // 64
  float* cwsgw = gw + FF;              // 2 (+pad)
  float* L = ws + 397456;              // 8*192*383 = 588288, 16-float aligned
  (void)ws_size; (void)n_in; (void)in_sizes; (void)out_size;

  hipLaunchKernelGGL(prep_all, dim3(BB * NN + 1), dim3(64), 0, stream,
                     nodes, w1, b1, w2, b2, g1, be1, g2, be2, w3, b3,
                     A, Bv, W2gT, cb, gw, cwsgw);
  hipLaunchKernelGGL(edge_mlp, dim3(NEDGE / 256), dim3(256), 0, stream,
                     A, Bv, W2gT, cb, gw, cwsgw, bidx, ridx, cidx, L,
                     (float4*)out);
  hipLaunchKernelGGL(argmax_scatter, dim3((SS * BB * NSINK) / 4), dim3(256), 0, stream,
                     L, gum, out);
}